// Round 2
// baseline (366.900 us; speedup 1.0000x reference)
//
#include <hip/hip_runtime.h>
#include <hip/hip_bf16.h>
#include <stdint.h>

#define NROWS 8192
#define KDIM  512
#define NC    11014
#define PADC  11136      // 87 * 128
#define CTILES 87        // column tiles of 128
#define RT    64         // row tiles of 128
#define STRIPS 8         // one strip per XCD (gridDim.x == 8 -> linear id % 8 == x)
#define TPS   11         // col-tiles per strip (last strip has 10)
#define NCHUNK (CTILES * 2)

#define BM 128
#define BN 128
#define BK 32

#define SS    30.0f
#define COSM  0.8253356149096783f
#define SINM  0.5646424733950354f
#define THv  (-0.8253356149096783f)
#define MMv   0.33878548403702126f

typedef __attribute__((ext_vector_type(4))) float  f32x4;
typedef __attribute__((ext_vector_type(8))) __bf16 bf16x8;

// async global->LDS, 16B per lane; LDS dest is wave-uniform base + lane*16.
__device__ __forceinline__ void async16(const void* g, void* l) {
  __builtin_amdgcn_global_load_lds(
      (const __attribute__((address_space(1))) unsigned int*)(uintptr_t)g,
      (__attribute__((address_space(3))) unsigned int*)(uint32_t)(uintptr_t)l,
      16, 0, 0);
}

// ---------------- kernel 0: L2-normalize rows of x,w -> bf16 (wave per row) --
__global__ void norm_kernel(const float* __restrict__ x, const float* __restrict__ w,
                            __hip_bfloat16* __restrict__ xn, __hip_bfloat16* __restrict__ wn) {
  const int wid  = blockIdx.x * 4 + (threadIdx.x >> 6);
  const int lane = threadIdx.x & 63;
  const bool isx = (wid < NROWS);
  const int r = isx ? wid : (wid - NROWS);
  const bool pad = (!isx) && (r >= NC);
  const float* p = isx ? (x + (size_t)r * KDIM) : (w + (size_t)r * KDIM);
  f32x4 a = {0.f, 0.f, 0.f, 0.f}, b = {0.f, 0.f, 0.f, 0.f};
  if (!pad) {
    a = ((const f32x4*)p)[2 * lane];
    b = ((const f32x4*)p)[2 * lane + 1];
  }
  float ss = a[0]*a[0] + a[1]*a[1] + a[2]*a[2] + a[3]*a[3]
           + b[0]*b[0] + b[1]*b[1] + b[2]*b[2] + b[3]*b[3];
#pragma unroll
  for (int d = 1; d < 64; d <<= 1) ss += __shfl_xor(ss, d);
  const float scale = pad ? 0.f : (1.0f / fmaxf(sqrtf(ss), 1e-12f));
  __hip_bfloat16* o = isx ? (xn + (size_t)r * KDIM) : (wn + (size_t)r * KDIM);
  bf16x8 ov;
#pragma unroll
  for (int e = 0; e < 4; ++e) ov[e]     = (__bf16)(a[e] * scale);
#pragma unroll
  for (int e = 0; e < 4; ++e) ov[e + 4] = (__bf16)(b[e] * scale);
  *(bf16x8*)(o + lane * 8) = ov;
}

// ---------------- kernel 1: bf16 MFMA GEMM + ArcFace + partials --------------
// Strip design: block = (strip, row-tile); loops TPS col-tiles.
__global__ __launch_bounds__(256, 2) void gemm_arc(
    const __hip_bfloat16* __restrict__ xn, const __hip_bfloat16* __restrict__ wn,
    const int* __restrict__ label, float* __restrict__ out,
    float2* __restrict__ parts) {
  // A tile [0,8192), B tile [8192,16384). Epilogue scratch overlays both:
  // wave w uses [w*4096, w*4096+4096).
  __shared__ __align__(16) char sm[16384];
  __shared__ int slbl[BM];

  const int tid  = threadIdx.x;
  const int w    = tid >> 6;
  const int lane = tid & 63;
  const int wr   = w >> 1, wc = w & 1;
  const int strip = blockIdx.x;          // == XCD id (gridDim.x==8)
  const int tr    = blockIdx.y;
  const int rowBase = tr * BM;

  if (tid < BM) slbl[tid] = label[rowBase + tid];

  // staging: wave w covers rows [w*32, w*32+32): lane -> row w*32 + (lane>>2),
  // k-bytes (lane&3)*16; LDS linear [row][k] rows of 64B.
  const __hip_bfloat16* ga = xn + (size_t)(rowBase + w * 32 + (lane >> 2)) * KDIM + (lane & 3) * 8;
  char* laBase = sm + w * 2048;
  char* lbBase = sm + 8192 + w * 2048;

  // fragment offsets: A row = wr*64 + m*16 + (lane&15); k-half = lane>>4
  const int aoff = (wr * 64 + (lane & 15)) * 64 + (lane >> 4) * 16;
  const int boff = 8192 + (wc * 64 + (lane & 15)) * 64 + (lane >> 4) * 16;

  const int g4 = lane >> 4;
  const int c4 = lane & 15;
  float* ep = (float*)(sm + w * 4096);   // 16 rows x 64 cols f32

  const int ctEnd = (strip == STRIPS - 1) ? CTILES : (strip * TPS + TPS);

  for (int ct = strip * TPS; ct < ctEnd; ++ct) {
    const int colBase = ct * BN;
    __syncthreads();   // epilogue scratch of previous ct is dead before restaging

    f32x4 acc[4][4];
#pragma unroll
    for (int m = 0; m < 4; ++m)
#pragma unroll
      for (int n = 0; n < 4; ++n)
        acc[m][n] = (f32x4){0.f, 0.f, 0.f, 0.f};

    const __hip_bfloat16* gb = wn + (size_t)(colBase + w * 32 + (lane >> 2)) * KDIM + (lane & 3) * 8;

    for (int kt = 0; kt < KDIM / BK; ++kt) {
      const __hip_bfloat16* pa = ga + kt * BK;
      const __hip_bfloat16* pb = gb + kt * BK;
      async16(pa,             laBase);
      async16(pa + 16 * KDIM, laBase + 1024);
      async16(pb,             lbBase);
      async16(pb + 16 * KDIM, lbBase + 1024);
      __syncthreads();

      bf16x8 af[4], bq[4];
#pragma unroll
      for (int m = 0; m < 4; ++m)
        af[m] = *(const bf16x8*)(sm + aoff + m * 1024);
#pragma unroll
      for (int n = 0; n < 4; ++n)
        bq[n] = *(const bf16x8*)(sm + boff + n * 1024);
#pragma unroll
      for (int m = 0; m < 4; ++m)
#pragma unroll
        for (int n = 0; n < 4; ++n)
          acc[m][n] = __builtin_amdgcn_mfma_f32_16x16x32_bf16(af[m], bq[n], acc[m][n], 0, 0, 0);
      __syncthreads();
    }

    // ---- epilogue: margin + partials + LDS-transposed nontemporal stores ----
#pragma unroll
    for (int m = 0; m < 4; ++m) {
#pragma unroll
      for (int j = 0; j < 4; ++j) {
        const int lrow = wr * 64 + m * 16 + g4 * 4 + j;
        const int grow = rowBase + lrow;
        const int rl   = slbl[lrow];
        float vred[4];
        float mx = -1e30f;
#pragma unroll
        for (int n = 0; n < 4; ++n) {
          const int gc = colBase + wc * 64 + n * 16 + c4;
          float c = acc[m][n][j];
          float logit = c * SS;
          if (gc == rl) {  // rare; execz-skipped
            float sine = sqrtf(fmaxf(0.f, 1.f - c * c));
            float phi  = c * COSM - sine * SINM;
            phi = (c > THv) ? phi : (c - MMv);
            logit = phi * SS;
          }
          ep[(g4 * 4 + j) * 64 + n * 16 + c4] = logit;
          vred[n] = (gc < NC) ? logit : -1e30f;
          mx = fmaxf(mx, vred[n]);
        }
#pragma unroll
        for (int d = 1; d < 16; d <<= 1) mx = fmaxf(mx, __shfl_xor(mx, d));
        float s = 0.f;
#pragma unroll
        for (int n = 0; n < 4; ++n)
          if (vred[n] > -1e29f) s += __expf(vred[n] - mx);
#pragma unroll
        for (int d = 1; d < 16; d <<= 1) s += __shfl_xor(s, d);
        if (c4 == 0) {
          parts[(size_t)(ct * 2 + wc) * NROWS + grow] = make_float2(mx, s);
        }
      }
      // read back transposed: per i, wave covers 4 rows x 256B contiguous
#pragma unroll
      for (int i = 0; i < 4; ++i) {
        const int idx = i * 64 + lane;
        const int r   = idx >> 4;
        const int c   = idx & 15;
        f32x4 val = *(const f32x4*)(ep + r * 64 + c * 4);
        const int grow2 = rowBase + wr * 64 + m * 16 + r;
        const int gc4   = colBase + wc * 64 + c * 4;
        float* dst = out + (size_t)grow2 * NC + gc4;
        if (gc4 + 3 < NC) {
          __builtin_nontemporal_store(val, (f32x4*)dst);
        } else {
#pragma unroll
          for (int e = 0; e < 4; ++e)
            if (gc4 + e < NC) dst[e] = val[e];
        }
      }
    }
  }
}

// ---------------- kernel 2: per-row logsumexp merge + NLL --------------------
__global__ void merge_loss(const float2* __restrict__ parts, const float* __restrict__ out,
                           const int* __restrict__ label, float* __restrict__ rowloss) {
  const int row = blockIdx.x * 256 + threadIdx.x;
  float M = -1e30f;
  for (int c = 0; c < NCHUNK; ++c) M = fmaxf(M, parts[(size_t)c * NROWS + row].x);
  float Ssum = 0.f;
  for (int c = 0; c < NCHUNK; ++c) {
    float2 p = parts[(size_t)c * NROWS + row];
    if (p.x > -1e29f) Ssum += p.y * __expf(p.x - M);
  }
  const float lse = M + logf(Ssum);
  const float lt  = out[(size_t)row * NC + label[row]];
  rowloss[row] = lse - lt;
}

// ---------------- kernel 3: deterministic mean ------------------------------
__global__ void final_loss(const float* __restrict__ rowloss, float* __restrict__ out_loss) {
  double s = 0.0;
  for (int i = threadIdx.x; i < NROWS; i += 256) s += (double)rowloss[i];
  __shared__ double sd[256];
  sd[threadIdx.x] = s;
  __syncthreads();
  for (int step = 128; step > 0; step >>= 1) {
    if (threadIdx.x < step) sd[threadIdx.x] += sd[threadIdx.x + step];
    __syncthreads();
  }
  if (threadIdx.x == 0) out_loss[0] = (float)(sd[0] / (double)NROWS);
}

extern "C" void kernel_launch(void* const* d_in, const int* in_sizes, int n_in,
                              void* d_out, int out_size, void* d_ws, size_t ws_size,
                              hipStream_t stream) {
  const float* x     = (const float*)d_in[0];
  const int*   label = (const int*)d_in[1];
  const float* w     = (const float*)d_in[2];
  float* out = (float*)d_out;

  char* ws = (char*)d_ws;
  __hip_bfloat16* xn = (__hip_bfloat16*)ws;                      //  8,388,608 B
  __hip_bfloat16* wn = (__hip_bfloat16*)(ws + 8388608);          // 11,403,264 B
  float2* parts      = (float2*)(ws + 19791872);                 // 11,403,264 B
  float*  rowloss    = (float*)(ws + 31195136);                  //     32,768 B

  norm_kernel<<<dim3((NROWS + PADC) / 4), dim3(256), 0, stream>>>(x, w, xn, wn);
  gemm_arc<<<dim3(STRIPS, RT), dim3(256), 0, stream>>>(xn, wn, label, out, parts);
  merge_loss<<<dim3(32), dim3(256), 0, stream>>>(parts, out, label, rowloss);
  final_loss<<<dim3(1), dim3(256), 0, stream>>>(rowloss, out + (size_t)NROWS * NC);
}

// Round 3
// 300.884 us; speedup vs baseline: 1.2194x; 1.2194x over previous
//
#include <hip/hip_runtime.h>
#include <hip/hip_bf16.h>
#include <stdint.h>

#define NROWS 8192
#define KDIM  512
#define NC    11014
#define PADC  11136      // 87 * 128
#define CTILES 87        // column tiles of 128
#define RT    64         // row tiles of 128
#define NCHUNK (CTILES * 2)

#define BM 128
#define BN 128
#define BK 32

#define SS    30.0f
#define COSM  0.8253356149096783f
#define SINM  0.5646424733950354f
#define THv  (-0.8253356149096783f)
#define MMv   0.33878548403702126f

typedef __attribute__((ext_vector_type(4))) float  f32x4;
typedef __attribute__((ext_vector_type(8))) __bf16 bf16x8;

// async global->LDS, 16B per lane; LDS dest is wave-uniform base + lane*16.
__device__ __forceinline__ void async16(const void* g, void* l) {
  __builtin_amdgcn_global_load_lds(
      (const __attribute__((address_space(1))) unsigned int*)(uintptr_t)g,
      (__attribute__((address_space(3))) unsigned int*)(uint32_t)(uintptr_t)l,
      16, 0, 0);
}

// ---------------- kernel 0: L2-normalize rows of x,w -> bf16 (wave per row) --
__global__ void norm_kernel(const float* __restrict__ x, const float* __restrict__ w,
                            __hip_bfloat16* __restrict__ xn, __hip_bfloat16* __restrict__ wn) {
  const int wid  = blockIdx.x * 4 + (threadIdx.x >> 6);
  const int lane = threadIdx.x & 63;
  const bool isx = (wid < NROWS);
  const int r = isx ? wid : (wid - NROWS);
  const bool pad = (!isx) && (r >= NC);
  const float* p = isx ? (x + (size_t)r * KDIM) : (w + (size_t)r * KDIM);
  f32x4 a = {0.f, 0.f, 0.f, 0.f}, b = {0.f, 0.f, 0.f, 0.f};
  if (!pad) {
    a = ((const f32x4*)p)[2 * lane];
    b = ((const f32x4*)p)[2 * lane + 1];
  }
  float ss = a[0]*a[0] + a[1]*a[1] + a[2]*a[2] + a[3]*a[3]
           + b[0]*b[0] + b[1]*b[1] + b[2]*b[2] + b[3]*b[3];
#pragma unroll
  for (int d = 1; d < 64; d <<= 1) ss += __shfl_xor(ss, d);
  const float scale = pad ? 0.f : (1.0f / fmaxf(sqrtf(ss), 1e-12f));
  __hip_bfloat16* o = isx ? (xn + (size_t)r * KDIM) : (wn + (size_t)r * KDIM);
  bf16x8 ov;
#pragma unroll
  for (int e = 0; e < 4; ++e) ov[e]     = (__bf16)(a[e] * scale);
#pragma unroll
  for (int e = 0; e < 4; ++e) ov[e + 4] = (__bf16)(b[e] * scale);
  *(bf16x8*)(o + lane * 8) = ov;
}

// ---------------- kernel 1: bf16 MFMA GEMM + ArcFace + partials --------------
// R1 structure (grid 87x64), new epilogue: cross-wave LDS bounce -> 512B-row
// contiguous nontemporal stores.
__global__ __launch_bounds__(256, 2) void gemm_arc(
    const __hip_bfloat16* __restrict__ xn, const __hip_bfloat16* __restrict__ wn,
    const int* __restrict__ label, float* __restrict__ out,
    float2* __restrict__ parts) {
  // K-loop: A tile [0,8192), B tile [8192,16384).
  // Epilogue: [32][128] f32 bounce tile overlays [0,16384).
  __shared__ __align__(16) char sm[16384];
  __shared__ int slbl[BM];

  const int tid  = threadIdx.x;
  const int w    = tid >> 6;
  const int lane = tid & 63;
  const int wr   = w >> 1, wc = w & 1;
  const int tc   = blockIdx.x;
  const int tr   = blockIdx.y;
  const int rowBase = tr * BM;
  const int colBase = tc * BN;

  if (tid < BM) slbl[tid] = label[rowBase + tid];

  f32x4 acc[4][4];
#pragma unroll
  for (int m = 0; m < 4; ++m)
#pragma unroll
    for (int n = 0; n < 4; ++n)
      acc[m][n] = (f32x4){0.f, 0.f, 0.f, 0.f};

  // staging: wave w covers rows [w*32, w*32+32): lane -> row w*32 + (lane>>2),
  // k-bytes (lane&3)*16; LDS linear [row][k] rows of 64B.
  const __hip_bfloat16* ga = xn + (size_t)(rowBase + w * 32 + (lane >> 2)) * KDIM + (lane & 3) * 8;
  const __hip_bfloat16* gb = wn + (size_t)(colBase + w * 32 + (lane >> 2)) * KDIM + (lane & 3) * 8;
  char* laBase = sm + w * 2048;
  char* lbBase = sm + 8192 + w * 2048;

  // fragment offsets: A row = wr*64 + m*16 + (lane&15); k-half = lane>>4
  const int aoff = (wr * 64 + (lane & 15)) * 64 + (lane >> 4) * 16;
  const int boff = 8192 + (wc * 64 + (lane & 15)) * 64 + (lane >> 4) * 16;

  for (int kt = 0; kt < KDIM / BK; ++kt) {
    const __hip_bfloat16* pa = ga + kt * BK;
    const __hip_bfloat16* pb = gb + kt * BK;
    async16(pa,             laBase);
    async16(pa + 16 * KDIM, laBase + 1024);
    async16(pb,             lbBase);
    async16(pb + 16 * KDIM, lbBase + 1024);
    __syncthreads();

    bf16x8 af[4], bq[4];
#pragma unroll
    for (int m = 0; m < 4; ++m)
      af[m] = *(const bf16x8*)(sm + aoff + m * 1024);
#pragma unroll
    for (int n = 0; n < 4; ++n)
      bq[n] = *(const bf16x8*)(sm + boff + n * 1024);
#pragma unroll
    for (int m = 0; m < 4; ++m)
#pragma unroll
      for (int n = 0; n < 4; ++n)
        acc[m][n] = __builtin_amdgcn_mfma_f32_16x16x32_bf16(af[m], bq[n], acc[m][n], 0, 0, 0);
    __syncthreads();
  }

  // ---- epilogue: margin + partials; bounce 32x128 f32 tile through LDS ----
  const int g4 = lane >> 4;
  const int c4 = lane & 15;
  float* ep = (float*)sm;  // [32][128] f32

#pragma unroll
  for (int m = 0; m < 4; ++m) {
#pragma unroll
    for (int j = 0; j < 4; ++j) {
      const int lrow = wr * 64 + m * 16 + g4 * 4 + j;
      const int grow = rowBase + lrow;
      const int rl   = slbl[lrow];
      float vred[4];
      float mx = -1e30f;
#pragma unroll
      for (int n = 0; n < 4; ++n) {
        const int gc = colBase + wc * 64 + n * 16 + c4;
        float c = acc[m][n][j];
        float logit = c * SS;
        if (gc == rl) {  // rare; execz-skipped
          float sine = sqrtf(fmaxf(0.f, 1.f - c * c));
          float phi  = c * COSM - sine * SINM;
          phi = (c > THv) ? phi : (c - MMv);
          logit = phi * SS;
        }
        // bounce-tile local row: wr*16 + g4*4 + j, col: wc*64 + n*16 + c4
        ep[(wr * 16 + g4 * 4 + j) * 128 + wc * 64 + n * 16 + c4] = logit;
        vred[n] = (gc < NC) ? logit : -1e30f;
        mx = fmaxf(mx, vred[n]);
      }
#pragma unroll
      for (int d = 1; d < 16; d <<= 1) mx = fmaxf(mx, __shfl_xor(mx, d));
      float s = 0.f;
#pragma unroll
      for (int n = 0; n < 4; ++n)
        if (vred[n] > -1e29f) s += __expf(vred[n] - mx);
#pragma unroll
      for (int d = 1; d < 16; d <<= 1) s += __shfl_xor(s, d);
      if (c4 == 0) {
        parts[(size_t)(tc * 2 + wc) * NROWS + grow] = make_float2(mx, s);
      }
    }
    __syncthreads();
    // readback: 32 rows x 512B; per thread-round 16B; wave covers 2 rows x 512B
#pragma unroll
    for (int i = 0; i < 4; ++i) {
      const int idx = i * 256 + tid;
      const int r   = idx >> 5;         // 0..31 local row
      const int ch  = idx & 31;         // 16B chunk within row
      f32x4 val = *(const f32x4*)(ep + r * 128 + ch * 4);
      const int grow2 = rowBase + (r >> 4) * 64 + m * 16 + (r & 15);
      const int gc    = colBase + ch * 4;
      float* dst = out + (size_t)grow2 * NC + gc;
      if (gc + 3 < NC) {
        __builtin_nontemporal_store(val, (f32x4*)dst);
      } else {
#pragma unroll
        for (int e = 0; e < 4; ++e)
          if (gc + e < NC) dst[e] = val[e];
      }
    }
    __syncthreads();
  }
}

// ---------------- kernel 2: per-row logsumexp merge + NLL --------------------
__global__ void merge_loss(const float2* __restrict__ parts, const float* __restrict__ out,
                           const int* __restrict__ label, float* __restrict__ rowloss) {
  const int row = blockIdx.x * 256 + threadIdx.x;
  float M = -1e30f;
  for (int c = 0; c < NCHUNK; ++c) M = fmaxf(M, parts[(size_t)c * NROWS + row].x);
  float Ssum = 0.f;
  for (int c = 0; c < NCHUNK; ++c) {
    float2 p = parts[(size_t)c * NROWS + row];
    if (p.x > -1e29f) Ssum += p.y * __expf(p.x - M);
  }
  const float lse = M + logf(Ssum);
  const float lt  = out[(size_t)row * NC + label[row]];
  rowloss[row] = lse - lt;
}

// ---------------- kernel 3: deterministic mean ------------------------------
__global__ void final_loss(const float* __restrict__ rowloss, float* __restrict__ out_loss) {
  double s = 0.0;
  for (int i = threadIdx.x; i < NROWS; i += 256) s += (double)rowloss[i];
  __shared__ double sd[256];
  sd[threadIdx.x] = s;
  __syncthreads();
  for (int step = 128; step > 0; step >>= 1) {
    if (threadIdx.x < step) sd[threadIdx.x] += sd[threadIdx.x + step];
    __syncthreads();
  }
  if (threadIdx.x == 0) out_loss[0] = (float)(sd[0] / (double)NROWS);
}

extern "C" void kernel_launch(void* const* d_in, const int* in_sizes, int n_in,
                              void* d_out, int out_size, void* d_ws, size_t ws_size,
                              hipStream_t stream) {
  const float* x     = (const float*)d_in[0];
  const int*   label = (const int*)d_in[1];
  const float* w     = (const float*)d_in[2];
  float* out = (float*)d_out;

  char* ws = (char*)d_ws;
  __hip_bfloat16* xn = (__hip_bfloat16*)ws;                      //  8,388,608 B
  __hip_bfloat16* wn = (__hip_bfloat16*)(ws + 8388608);          // 11,403,264 B
  float2* parts      = (float2*)(ws + 19791872);                 // 11,403,264 B
  float*  rowloss    = (float*)(ws + 31195136);                  //     32,768 B

  norm_kernel<<<dim3((NROWS + PADC) / 4), dim3(256), 0, stream>>>(x, w, xn, wn);
  gemm_arc<<<dim3(CTILES, RT), dim3(256), 0, stream>>>(xn, wn, label, out, parts);
  merge_loss<<<dim3(32), dim3(256), 0, stream>>>(parts, out, label, rowloss);
  final_loss<<<dim3(1), dim3(256), 0, stream>>>(rowloss, out + (size_t)NROWS * NC);
}